// Round 6
// baseline (289.240 us; speedup 1.0000x reference)
//
#include <hip/hip_runtime.h>
#include <cstdint>
#include <cstddef>
#include <cmath>

// ---------------------------------------------------------------------------
// GCN: 3 layers. CSR (by dst) built once, then:
//   L1: GEMM1(x 256->128, bf16 MFMA) -> agg(+b1,relu)
//   L2: GEMM2(128->128)              -> agg(+b2,relu)
//   L3: agg (no bias/relu)           -> GEMM3(128->40) + fused bias+log_softmax
// R1: parallel scan. R2: MFMA GEMM + packed W. R3: bf16 h, packed edges.
// R4: layer-3 commuted; agg = 4 edge-groups x 16 lanes x 8 feats.
// R5: fill scatters 4B src-only (8x->4x write amp; norm moved into agg);
//     agg edge loop unrolled 2x (8 gathers in flight/wave).
// ---------------------------------------------------------------------------

typedef __attribute__((ext_vector_type(8))) short short8;
typedef __attribute__((ext_vector_type(4))) float f32x4;

__device__ __forceinline__ ushort f2bf(float f) {
  union { float f; uint32_t u; } x; x.f = f;
  uint32_t r = x.u + 0x7fffu + ((x.u >> 16) & 1u);  // RNE
  return (ushort)(r >> 16);
}
__device__ __forceinline__ float bf2f(ushort u) {
  union { uint32_t u; float f; } x; x.u = ((uint32_t)u) << 16;
  return x.f;
}

// ---------------- CSR build ----------------
__global__ void hist_kernel(const int* __restrict__ dst, int* __restrict__ deg, int E) {
  int e = blockIdx.x * blockDim.x + threadIdx.x;
  if (e < E) atomicAdd(&deg[dst[e]], 1);
}

__global__ __launch_bounds__(256) void bsum_kernel(const int* __restrict__ deg,
                                                   int* __restrict__ bsum, int n) {
  __shared__ int s[256];
  const int t = threadIdx.x;
  const int i = blockIdx.x * 256 + t;
  s[t] = (i < n) ? deg[i] : 0;
  __syncthreads();
#pragma unroll
  for (int off = 128; off >= 1; off >>= 1) {
    if (t < off) s[t] += s[t + off];
    __syncthreads();
  }
  if (t == 0) bsum[blockIdx.x] = s[0];
}

__global__ __launch_bounds__(1024) void bscan_kernel(const int* __restrict__ bsum,
                                                     int* __restrict__ bbase,
                                                     int* __restrict__ offsets,
                                                     int nb, int n) {
  __shared__ int s[1024];
  const int t = threadIdx.x;
  s[t] = (t < nb) ? bsum[t] : 0;
  __syncthreads();
  for (int off = 1; off < 1024; off <<= 1) {
    int v = (t >= off) ? s[t - off] : 0;
    __syncthreads();
    s[t] += v;
    __syncthreads();
  }
  if (t < nb) bbase[t] = (t > 0) ? s[t - 1] : 0;
  if (t == 0) offsets[n] = s[nb - 1];
}

__global__ __launch_bounds__(256) void offs_kernel(const int* __restrict__ deg,
                                                   const int* __restrict__ bbase,
                                                   int* __restrict__ offsets,
                                                   int* __restrict__ cursor,
                                                   float* __restrict__ dinv, int n) {
  __shared__ int s[256];
  const int t = threadIdx.x;
  const int i = blockIdx.x * 256 + t;
  const int d = (i < n) ? deg[i] : 0;
  s[t] = d;
  __syncthreads();
  for (int off = 1; off < 256; off <<= 1) {
    int v = (t >= off) ? s[t - off] : 0;
    __syncthreads();
    s[t] += v;
    __syncthreads();
  }
  if (i < n) {
    const int excl = bbase[blockIdx.x] + s[t] - d;
    offsets[i] = excl;
    cursor[i]  = excl;
    dinv[i]    = rsqrtf((float)(d + 1));
  }
}

// R5: scatter only the 4B source index (halves partial-line writebacks).
__global__ void fill_kernel(const int* __restrict__ src, const int* __restrict__ dst,
                            int* __restrict__ cursor, int* __restrict__ eidx, int E) {
  int e = blockIdx.x * blockDim.x + threadIdx.x;
  if (e >= E) return;
  int s = src[e], d = dst[e];
  int p = atomicAdd(&cursor[d], 1);
  eidx[p] = s;
}

// ---------------- W pre-pack into MFMA B-fragment order ----------------
__global__ __launch_bounds__(256) void pack_w_kernel(const float* __restrict__ W,
                                                     ushort* __restrict__ Wp,
                                                     int K, int N, int NF) {
  const int idx  = blockIdx.x * blockDim.x + threadIdx.x;
  const int lane = idx & 63;
  const int nf   = (idx >> 6) % NF;
  const int g    = idx / (64 * NF);
  if (g * 32 >= K) return;
  const int n  = nf * 16 + (lane & 15);
  const int kb = g * 32 + (lane >> 4) * 8;
  ushort v[8];
#pragma unroll
  for (int j = 0; j < 8; ++j) {
    const float f = (n < N) ? W[(size_t)(kb + j) * N + n] : 0.f;
    v[j] = f2bf(f);
  }
  *(short8*)&Wp[((size_t)(g * NF + nf) * 64 + lane) * 8] = *(short8*)v;
}

// ---------------- MFMA GEMM: C[M,N] = A[M,K] @ W[K,N], bf16 out ----------------
template <int NF, bool AF32>
__global__ __launch_bounds__(256) void mfma_gemm_kernel(const void* __restrict__ Av,
                                                        const ushort* __restrict__ Wp,
                                                        ushort* __restrict__ C,
                                                        int M, int N, int K) {
  __shared__ ushort Atile[64 * 64];
  const int tid  = threadIdx.x;
  const int lane = tid & 63;
  const int wave = tid >> 6;
  const int brow = blockIdx.x * 64;

  f32x4 acc[NF];
#pragma unroll
  for (int nf = 0; nf < NF; ++nf) acc[nf] = (f32x4){0.f, 0.f, 0.f, 0.f};

  const int arow = wave * 16 + (lane & 15);
  const int ahi  = lane >> 4;
  const int row0 = tid >> 3;
  const int kc0  = tid & 7;

  for (int k0 = 0; k0 < K; k0 += 64) {
    if (k0) __syncthreads();
#pragma unroll
    for (int c = 0; c < 2; ++c) {
      const int row = row0 + c * 32;
      const int gr  = brow + row;
      short8 v = (short8){0, 0, 0, 0, 0, 0, 0, 0};
      if (gr < M) {
        if constexpr (AF32) {
          const float* A = (const float*)Av + (size_t)gr * K + k0 + kc0 * 8;
          const float4 f0 = *(const float4*)A;
          const float4 f1 = *(const float4*)(A + 4);
          v[0] = (short)f2bf(f0.x); v[1] = (short)f2bf(f0.y);
          v[2] = (short)f2bf(f0.z); v[3] = (short)f2bf(f0.w);
          v[4] = (short)f2bf(f1.x); v[5] = (short)f2bf(f1.y);
          v[6] = (short)f2bf(f1.z); v[7] = (short)f2bf(f1.w);
        } else {
          v = *(const short8*)((const ushort*)Av + (size_t)gr * K + k0 + kc0 * 8);
        }
      }
      *(short8*)&Atile[row * 64 + ((kc0 ^ (row & 7)) * 8)] = v;
    }
    __syncthreads();

    const int gbase = (k0 >> 5) * NF;
#pragma unroll
    for (int kk = 0; kk < 2; ++kk) {
      const int kc = kk * 4 + ahi;
      const short8 a =
          *(const short8*)&Atile[arow * 64 + ((kc ^ (arow & 7)) * 8)];
      const ushort* wp = Wp + ((size_t)(gbase + kk * NF) * 64 + lane) * 8;
#pragma unroll
      for (int nf = 0; nf < NF; ++nf) {
        const short8 b = *(const short8*)(wp + (size_t)nf * 64 * 8);
        acc[nf] = __builtin_amdgcn_mfma_f32_16x16x32_bf16(a, b, acc[nf], 0, 0, 0);
      }
    }
  }

  const int crow0 = brow + wave * 16 + (lane >> 4) * 4;
  const int ccol  = lane & 15;
#pragma unroll
  for (int nf = 0; nf < NF; ++nf) {
    const int col = nf * 16 + ccol;
    if (col < N) {
#pragma unroll
      for (int r = 0; r < 4; ++r) {
        const int row = crow0 + r;
        if (row < M) C[(size_t)row * N + col] = f2bf(acc[nf][r]);
      }
    }
  }
}

// ------- GEMM3 + fused bias + log_softmax: out[M,40] = lsm(A[M,128] @ W3 + b3) -------
__global__ __launch_bounds__(256) void mfma_gemm_lsm_kernel(const ushort* __restrict__ A,
                                                            const ushort* __restrict__ Wp,
                                                            const float* __restrict__ bias,
                                                            float* __restrict__ out,
                                                            int M, int N, int K) {
  constexpr int NF = 3;
  __shared__ ushort Atile[64 * 64];
  const int tid  = threadIdx.x;
  const int lane = tid & 63;
  const int wave = tid >> 6;
  const int brow = blockIdx.x * 64;

  f32x4 acc[NF];
#pragma unroll
  for (int nf = 0; nf < NF; ++nf) acc[nf] = (f32x4){0.f, 0.f, 0.f, 0.f};

  const int arow = wave * 16 + (lane & 15);
  const int ahi  = lane >> 4;
  const int row0 = tid >> 3;
  const int kc0  = tid & 7;

  for (int k0 = 0; k0 < K; k0 += 64) {
    if (k0) __syncthreads();
#pragma unroll
    for (int c = 0; c < 2; ++c) {
      const int row = row0 + c * 32;
      const int gr  = brow + row;
      short8 v = (short8){0, 0, 0, 0, 0, 0, 0, 0};
      if (gr < M)
        v = *(const short8*)&A[(size_t)gr * K + k0 + kc0 * 8];
      *(short8*)&Atile[row * 64 + ((kc0 ^ (row & 7)) * 8)] = v;
    }
    __syncthreads();

    const int gbase = (k0 >> 5) * NF;
#pragma unroll
    for (int kk = 0; kk < 2; ++kk) {
      const int kc = kk * 4 + ahi;
      const short8 a =
          *(const short8*)&Atile[arow * 64 + ((kc ^ (arow & 7)) * 8)];
      const ushort* wp = Wp + ((size_t)(gbase + kk * NF) * 64 + lane) * 8;
#pragma unroll
      for (int nf = 0; nf < NF; ++nf) {
        const short8 b = *(const short8*)(wp + (size_t)nf * 64 * 8);
        acc[nf] = __builtin_amdgcn_mfma_f32_16x16x32_bf16(a, b, acc[nf], 0, 0, 0);
      }
    }
  }

  // epilogue: +bias, then row-wise log_softmax over 40 cols (16-lane quarter).
  const int ccol  = lane & 15;
  const int crow0 = brow + wave * 16 + (lane >> 4) * 4;
  float bv[NF];
#pragma unroll
  for (int nf = 0; nf < NF; ++nf) {
    const int col = nf * 16 + ccol;
    bv[nf] = (col < N) ? bias[col] : 0.f;
  }
  const bool v2ok = (32 + ccol) < N;
#pragma unroll
  for (int r = 0; r < 4; ++r) {
    const float v0 = acc[0][r] + bv[0];
    const float v1 = acc[1][r] + bv[1];
    const float v2 = acc[2][r] + bv[2];
    float m = fmaxf(v0, v1);
    if (v2ok) m = fmaxf(m, v2);
#pragma unroll
    for (int o = 8; o >= 1; o >>= 1) m = fmaxf(m, __shfl_xor(m, o, 64));
    float s = expf(v0 - m) + expf(v1 - m) + (v2ok ? expf(v2 - m) : 0.f);
#pragma unroll
    for (int o = 8; o >= 1; o >>= 1) s += __shfl_xor(s, o, 64);
    const float mls = m + logf(s);
    const int row = crow0 + r;
    if (row < M) {
      out[(size_t)row * N + ccol]      = v0 - mls;
      out[(size_t)row * N + 16 + ccol] = v1 - mls;
      if (v2ok) out[(size_t)row * N + 32 + ccol] = v2 - mls;
    }
  }
}

// ---------------- Aggregation: 4 edge-groups x 16 lanes x 8 features ----------------
// One wave per node; 2x unrolled edge loop (8 gathers in flight per wave).
// norm = dinv[src]*dinv[node] computed here (R5: fill no longer stores it).
template <bool BIAS_RELU>
__global__ __launch_bounds__(256) void agg4_kernel(const ushort* __restrict__ h,
                                                   const int* __restrict__ offsets,
                                                   const int* __restrict__ eidx,
                                                   const float* __restrict__ dinv,
                                                   const float* __restrict__ bias,
                                                   ushort* __restrict__ out, int n) {
  const int wave = threadIdx.x >> 6;
  const int lane = threadIdx.x & 63;
  const int node = blockIdx.x * 4 + wave;
  if (node >= n) return;
  const int eg = lane >> 4;        // edge group 0..3
  const int f0 = (lane & 15) * 8;  // features f0..f0+7
  const float di = dinv[node];

  float acc[8];
#pragma unroll
  for (int j = 0; j < 8; ++j) acc[j] = 0.f;

  const int start = offsets[node];
  const int end   = offsets[node + 1];
  for (int eb = start; eb < end; eb += 8) {
    const int e0 = eb + eg;
    const int e1 = e0 + 4;
    if (e0 < end) {
      const int   s0 = eidx[e0];
      const float w0 = dinv[s0] * di;
      const short8 hv0 = *(const short8*)&h[(size_t)s0 * 128 + f0];
      if (e1 < end) {
        const int   s1 = eidx[e1];
        const float w1 = dinv[s1] * di;
        const short8 hv1 = *(const short8*)&h[(size_t)s1 * 128 + f0];
#pragma unroll
        for (int j = 0; j < 8; ++j) {
          acc[j] = fmaf(bf2f((ushort)hv0[j]), w0, acc[j]);
          acc[j] = fmaf(bf2f((ushort)hv1[j]), w1, acc[j]);
        }
      } else {
#pragma unroll
        for (int j = 0; j < 8; ++j) acc[j] = fmaf(bf2f((ushort)hv0[j]), w0, acc[j]);
      }
    }
  }
  // reduce across the 4 edge groups
#pragma unroll
  for (int j = 0; j < 8; ++j) {
    acc[j] += __shfl_xor(acc[j], 16, 64);
    acc[j] += __shfl_xor(acc[j], 32, 64);
  }
  if (eg == 0) {
    const float di2 = di * di;
    const short8 hs = *(const short8*)&h[(size_t)node * 128 + f0];
    ushort o[8];
#pragma unroll
    for (int j = 0; j < 8; ++j) {
      float a = fmaf(bf2f((ushort)hs[j]), di2, acc[j]);
      if (BIAS_RELU) a = fmaxf(a + bias[f0 + j], 0.f);
      o[j] = f2bf(a);
    }
    *(short8*)&out[(size_t)node * 128 + f0] = *(short8*)o;
  }
}

extern "C" void kernel_launch(void* const* d_in, const int* in_sizes, int n_in,
                              void* d_out, int out_size, void* d_ws, size_t ws_size,
                              hipStream_t stream) {
  const float* x  = (const float*)d_in[0];
  const int*   ei = (const int*)d_in[1];
  const float* W1 = (const float*)d_in[2];
  const float* b1 = (const float*)d_in[3];
  const float* W2 = (const float*)d_in[4];
  const float* b2 = (const float*)d_in[5];
  const float* W3 = (const float*)d_in[6];
  const float* b3 = (const float*)d_in[7];

  const int h1   = in_sizes[3];        // 128
  const int h2   = in_sizes[5];        // 128
  const int ncls = in_sizes[7];        // 40
  const int fin  = in_sizes[2] / h1;   // 256
  const int n    = in_sizes[0] / fin;  // 50000
  const int E    = in_sizes[1] / 2;    // 800000

  const int* src = ei;
  const int* dst = ei + E;

  char* p = (char*)d_ws;
  auto alloc = [&](size_t bytes) {
    char* r = p;
    p += (bytes + 255) & ~size_t(255);
    return r;
  };
  float*  dinv  = (float*)alloc((size_t)n * 4);
  int*    deg   = (int*)alloc((size_t)n * 4);
  int*    offs  = (int*)alloc((size_t)(n + 1) * 4);
  int*    curs  = (int*)alloc((size_t)n * 4);
  int*    bsum  = (int*)alloc(1024 * 4);
  int*    bbase = (int*)alloc(1024 * 4);
  int*    eidx  = (int*)alloc((size_t)E * 4);
  ushort* hf    = (ushort*)alloc((size_t)n * h1 * 2);  // ping
  ushort* hb    = (ushort*)alloc((size_t)n * h1 * 2);  // pong
  ushort* Wp1   = (ushort*)alloc((size_t)(fin / 32) * 8 * 64 * 8 * 2);
  ushort* Wp2   = (ushort*)alloc((size_t)(h1 / 32) * 8 * 64 * 8 * 2);
  ushort* Wp3   = (ushort*)alloc((size_t)(h2 / 32) * 3 * 64 * 8 * 2);

  const int nb = (n + 255) / 256;

  // --- CSR build ---
  hipMemsetAsync(deg, 0, (size_t)n * 4, stream);
  hist_kernel<<<(E + 255) / 256, 256, 0, stream>>>(dst, deg, E);
  bsum_kernel<<<nb, 256, 0, stream>>>(deg, bsum, n);
  bscan_kernel<<<1, 1024, 0, stream>>>(bsum, bbase, offs, nb, n);
  offs_kernel<<<nb, 256, 0, stream>>>(deg, bbase, offs, curs, dinv, n);
  fill_kernel<<<(E + 255) / 256, 256, 0, stream>>>(src, dst, curs, eidx, E);

  // --- pack weights (fragment order, bf16) ---
  {
    int t1 = (fin / 32) * 8 * 64;
    int t2 = (h1 / 32) * 8 * 64;
    int t3 = (h2 / 32) * 3 * 64;
    pack_w_kernel<<<(t1 + 255) / 256, 256, 0, stream>>>(W1, Wp1, fin, h1, 8);
    pack_w_kernel<<<(t2 + 255) / 256, 256, 0, stream>>>(W2, Wp2, h1, h2, 8);
    pack_w_kernel<<<(t3 + 255) / 256, 256, 0, stream>>>(W3, Wp3, h2, ncls, 3);
  }

  const int gblocks = (n + 63) / 64;
  const int ablocks = (n + 3) / 4;

  // --- layer 1 ---
  mfma_gemm_kernel<8, true><<<gblocks, 256, 0, stream>>>(x, Wp1, hf, n, h1, fin);
  agg4_kernel<true><<<ablocks, 256, 0, stream>>>(hf, offs, eidx, dinv, b1, hb, n);
  // --- layer 2 ---
  mfma_gemm_kernel<8, false><<<gblocks, 256, 0, stream>>>(hb, Wp2, hf, n, h2, h1);
  agg4_kernel<true><<<ablocks, 256, 0, stream>>>(hf, offs, eidx, dinv, b2, hb, n);
  // --- layer 3: aggregate first (agg and GEMM commute), then GEMM+LSM ---
  agg4_kernel<false><<<ablocks, 256, 0, stream>>>(hb, offs, eidx, dinv, nullptr, hf, n);
  mfma_gemm_lsm_kernel<<<gblocks, 256, 0, stream>>>(hf, Wp3, b3, (float*)d_out,
                                                    n, ncls, h2);
}

// Round 7
// 216.817 us; speedup vs baseline: 1.3340x; 1.3340x over previous
//
#include <hip/hip_runtime.h>
#include <cstdint>
#include <cstddef>
#include <cmath>

// ---------------------------------------------------------------------------
// GCN: 3 layers. CSR (by dst) built once, then:
//   L1: GEMM1(x 256->128, bf16 MFMA) -> agg(+b1,relu)
//   L2: GEMM2(128->128)              -> agg(+b2,relu)
//   L3: agg (no bias/relu)           -> GEMM3(128->40) + fused bias+log_softmax
// R2: MFMA GEMM + packed W. R3: bf16 h. R4: layer-3 commuted; agg4.
// R6 post-mortem: scatter write-amp is per-LINE (cross-XCD partial-dirty
//   writebacks), not per-byte. R7: 2-level bucket sort (bucket = dst>>8):
//   k1 LDS bucket hist -> k2 scan -> k3 per-wg LDS counting sort + chunked
//   writeout -> k4 per-bucket offs/dinv -> k5 per-bucket exact scatter into
//   single-XCD-owned 32KB regions. epair reverted to int2{src,norm}.
//   Requires n <= 65536 (256 nodes/bucket, <=256 buckets).
// ---------------------------------------------------------------------------

typedef __attribute__((ext_vector_type(8))) short short8;
typedef __attribute__((ext_vector_type(4))) float f32x4;

constexpr int EPB = 4096;  // edges per workgroup in bucket hist/scatter

__device__ __forceinline__ ushort f2bf(float f) {
  union { float f; uint32_t u; } x; x.f = f;
  uint32_t r = x.u + 0x7fffu + ((x.u >> 16) & 1u);  // RNE
  return (ushort)(r >> 16);
}
__device__ __forceinline__ float bf2f(ushort u) {
  union { uint32_t u; float f; } x; x.u = ((uint32_t)u) << 16;
  return x.f;
}

// ---------------- CSR build: 2-level bucket sort ----------------
// k1: per-wg LDS histogram by bucket (dst>>8), one global atomic per (wg,bucket)
__global__ __launch_bounds__(256) void bucket_hist_kernel(const int* __restrict__ dst,
                                                          int* __restrict__ bucket_count,
                                                          int E) {
  __shared__ int h[256];
  const int t  = threadIdx.x;
  const int e0 = blockIdx.x * EPB;
  const int myE = min(EPB, E - e0);
  h[t] = 0;
  __syncthreads();
  for (int i = t; i < myE; i += 256) atomicAdd(&h[dst[e0 + i] >> 8], 1);
  __syncthreads();
  if (h[t]) atomicAdd(&bucket_count[t], h[t]);
}

// k2: single block scans bucket counts -> bucket_offs, cursor; offs[n] = E
__global__ __launch_bounds__(256) void bucket_scan_kernel(const int* __restrict__ bucket_count,
                                                          int* __restrict__ bucket_offs,
                                                          int* __restrict__ bucket_cursor,
                                                          int* __restrict__ offs,
                                                          int nbuck, int n) {
  __shared__ int s[256];
  const int t = threadIdx.x;
  const int c = (t < nbuck) ? bucket_count[t] : 0;
  s[t] = c;
  __syncthreads();
  for (int off = 1; off < 256; off <<= 1) {
    int v = (t >= off) ? s[t - off] : 0;
    __syncthreads();
    s[t] += v;
    __syncthreads();
  }
  if (t < nbuck) {
    bucket_offs[t]   = s[t] - c;
    bucket_cursor[t] = s[t] - c;
  }
  if (t == 255) {
    bucket_offs[nbuck] = s[255];
    offs[n] = s[255];
  }
}

// k3: per-wg LDS counting sort of EPB edges by bucket, chunked coalesced writeout
__global__ __launch_bounds__(256) void bucket_scatter_kernel(const int* __restrict__ src,
                                                             const int* __restrict__ dst,
                                                             int* __restrict__ bucket_cursor,
                                                             int2* __restrict__ staged,
                                                             int E, int nbuck) {
  __shared__ int hist[256], s[256], lstart[256], cbase[256], lcur[256];
  __shared__ int2 stage[EPB];  // 32 KB
  const int t  = threadIdx.x;
  const int e0 = blockIdx.x * EPB;
  const int myE = min(EPB, E - e0);
  hist[t] = 0;
  __syncthreads();
  for (int i = t; i < myE; i += 256) atomicAdd(&hist[dst[e0 + i] >> 8], 1);
  __syncthreads();
  const int c = hist[t];
  s[t] = c;
  __syncthreads();
  for (int off = 1; off < 256; off <<= 1) {
    int v = (t >= off) ? s[t - off] : 0;
    __syncthreads();
    s[t] += v;
    __syncthreads();
  }
  lstart[t] = s[t] - c;
  lcur[t]   = s[t] - c;
  cbase[t]  = (c > 0 && t < nbuck) ? atomicAdd(&bucket_cursor[t], c) : 0;
  __syncthreads();
  for (int i = t; i < myE; i += 256) {
    const int sv = src[e0 + i], dv = dst[e0 + i];
    const int slot = atomicAdd(&lcur[dv >> 8], 1);
    stage[slot] = make_int2(sv, dv);
  }
  __syncthreads();
  for (int i = t; i < myE; i += 256) {
    const int2 sd = stage[i];
    const int b = sd.y >> 8;
    staged[cbase[b] + (i - lstart[b])] = sd;
  }
}

// k4: one wg per bucket: per-dst hist + scan -> offs, dinv (coalesced writes)
__global__ __launch_bounds__(256) void bucket_csr_kernel(const int2* __restrict__ staged,
                                                         const int* __restrict__ bucket_offs,
                                                         int* __restrict__ offs,
                                                         float* __restrict__ dinv, int n) {
  __shared__ int cnt[256], s[256];
  const int t = threadIdx.x, b = blockIdx.x;
  cnt[t] = 0;
  __syncthreads();
  const int ebeg = bucket_offs[b], eend = bucket_offs[b + 1];
  for (int i = ebeg + t; i < eend; i += 256) atomicAdd(&cnt[staged[i].y & 255], 1);
  __syncthreads();
  const int c = cnt[t];
  s[t] = c;
  __syncthreads();
  for (int off = 1; off < 256; off <<= 1) {
    int v = (t >= off) ? s[t - off] : 0;
    __syncthreads();
    s[t] += v;
    __syncthreads();
  }
  const int node = (b << 8) + t;
  if (node < n) {
    offs[node] = ebeg + s[t] - c;
    dinv[node] = rsqrtf((float)(c + 1));  // +1 self-loop
  }
}

// k5: one wg per bucket: exact-position scatter via LDS cursors into the
// bucket's contiguous region (single-XCD-owned lines -> no write amp).
__global__ __launch_bounds__(256) void bucket_fill_kernel(const int2* __restrict__ staged,
                                                          const int* __restrict__ bucket_offs,
                                                          const float* __restrict__ dinv,
                                                          int2* __restrict__ epair, int n) {
  __shared__ int cnt[256], s[256], cur[256];
  const int t = threadIdx.x, b = blockIdx.x;
  cnt[t] = 0;
  __syncthreads();
  const int ebeg = bucket_offs[b], eend = bucket_offs[b + 1];
  for (int i = ebeg + t; i < eend; i += 256) atomicAdd(&cnt[staged[i].y & 255], 1);
  __syncthreads();
  const int c = cnt[t];
  s[t] = c;
  __syncthreads();
  for (int off = 1; off < 256; off <<= 1) {
    int v = (t >= off) ? s[t - off] : 0;
    __syncthreads();
    s[t] += v;
    __syncthreads();
  }
  cur[t] = ebeg + s[t] - c;
  __syncthreads();
  for (int i = ebeg + t; i < eend; i += 256) {
    const int2 sd = staged[i];
    const int pos = atomicAdd(&cur[sd.y & 255], 1);
    epair[pos] = make_int2(sd.x, __float_as_int(dinv[sd.x] * dinv[sd.y]));
  }
}

// ---------------- W pre-pack into MFMA B-fragment order ----------------
__global__ __launch_bounds__(256) void pack_w_kernel(const float* __restrict__ W,
                                                     ushort* __restrict__ Wp,
                                                     int K, int N, int NF) {
  const int idx  = blockIdx.x * blockDim.x + threadIdx.x;
  const int lane = idx & 63;
  const int nf   = (idx >> 6) % NF;
  const int g    = idx / (64 * NF);
  if (g * 32 >= K) return;
  const int n  = nf * 16 + (lane & 15);
  const int kb = g * 32 + (lane >> 4) * 8;
  ushort v[8];
#pragma unroll
  for (int j = 0; j < 8; ++j) {
    const float f = (n < N) ? W[(size_t)(kb + j) * N + n] : 0.f;
    v[j] = f2bf(f);
  }
  *(short8*)&Wp[((size_t)(g * NF + nf) * 64 + lane) * 8] = *(short8*)v;
}

// ---------------- MFMA GEMM: C[M,N] = A[M,K] @ W[K,N], bf16 out ----------------
template <int NF, bool AF32>
__global__ __launch_bounds__(256) void mfma_gemm_kernel(const void* __restrict__ Av,
                                                        const ushort* __restrict__ Wp,
                                                        ushort* __restrict__ C,
                                                        int M, int N, int K) {
  __shared__ ushort Atile[64 * 64];
  const int tid  = threadIdx.x;
  const int lane = tid & 63;
  const int wave = tid >> 6;
  const int brow = blockIdx.x * 64;

  f32x4 acc[NF];
#pragma unroll
  for (int nf = 0; nf < NF; ++nf) acc[nf] = (f32x4){0.f, 0.f, 0.f, 0.f};

  const int arow = wave * 16 + (lane & 15);
  const int ahi  = lane >> 4;
  const int row0 = tid >> 3;
  const int kc0  = tid & 7;

  for (int k0 = 0; k0 < K; k0 += 64) {
    if (k0) __syncthreads();
#pragma unroll
    for (int c = 0; c < 2; ++c) {
      const int row = row0 + c * 32;
      const int gr  = brow + row;
      short8 v = (short8){0, 0, 0, 0, 0, 0, 0, 0};
      if (gr < M) {
        if constexpr (AF32) {
          const float* A = (const float*)Av + (size_t)gr * K + k0 + kc0 * 8;
          const float4 f0 = *(const float4*)A;
          const float4 f1 = *(const float4*)(A + 4);
          v[0] = (short)f2bf(f0.x); v[1] = (short)f2bf(f0.y);
          v[2] = (short)f2bf(f0.z); v[3] = (short)f2bf(f0.w);
          v[4] = (short)f2bf(f1.x); v[5] = (short)f2bf(f1.y);
          v[6] = (short)f2bf(f1.z); v[7] = (short)f2bf(f1.w);
        } else {
          v = *(const short8*)((const ushort*)Av + (size_t)gr * K + k0 + kc0 * 8);
        }
      }
      *(short8*)&Atile[row * 64 + ((kc0 ^ (row & 7)) * 8)] = v;
    }
    __syncthreads();

    const int gbase = (k0 >> 5) * NF;
#pragma unroll
    for (int kk = 0; kk < 2; ++kk) {
      const int kc = kk * 4 + ahi;
      const short8 a =
          *(const short8*)&Atile[arow * 64 + ((kc ^ (arow & 7)) * 8)];
      const ushort* wp = Wp + ((size_t)(gbase + kk * NF) * 64 + lane) * 8;
#pragma unroll
      for (int nf = 0; nf < NF; ++nf) {
        const short8 b = *(const short8*)(wp + (size_t)nf * 64 * 8);
        acc[nf] = __builtin_amdgcn_mfma_f32_16x16x32_bf16(a, b, acc[nf], 0, 0, 0);
      }
    }
  }

  const int crow0 = brow + wave * 16 + (lane >> 4) * 4;
  const int ccol  = lane & 15;
#pragma unroll
  for (int nf = 0; nf < NF; ++nf) {
    const int col = nf * 16 + ccol;
    if (col < N) {
#pragma unroll
      for (int r = 0; r < 4; ++r) {
        const int row = crow0 + r;
        if (row < M) C[(size_t)row * N + col] = f2bf(acc[nf][r]);
      }
    }
  }
}

// ------- GEMM3 + fused bias + log_softmax: out[M,40] = lsm(A[M,128] @ W3 + b3) -------
__global__ __launch_bounds__(256) void mfma_gemm_lsm_kernel(const ushort* __restrict__ A,
                                                            const ushort* __restrict__ Wp,
                                                            const float* __restrict__ bias,
                                                            float* __restrict__ out,
                                                            int M, int N, int K) {
  constexpr int NF = 3;
  __shared__ ushort Atile[64 * 64];
  const int tid  = threadIdx.x;
  const int lane = tid & 63;
  const int wave = tid >> 6;
  const int brow = blockIdx.x * 64;

  f32x4 acc[NF];
#pragma unroll
  for (int nf = 0; nf < NF; ++nf) acc[nf] = (f32x4){0.f, 0.f, 0.f, 0.f};

  const int arow = wave * 16 + (lane & 15);
  const int ahi  = lane >> 4;
  const int row0 = tid >> 3;
  const int kc0  = tid & 7;

  for (int k0 = 0; k0 < K; k0 += 64) {
    if (k0) __syncthreads();
#pragma unroll
    for (int c = 0; c < 2; ++c) {
      const int row = row0 + c * 32;
      const int gr  = brow + row;
      short8 v = (short8){0, 0, 0, 0, 0, 0, 0, 0};
      if (gr < M)
        v = *(const short8*)&A[(size_t)gr * K + k0 + kc0 * 8];
      *(short8*)&Atile[row * 64 + ((kc0 ^ (row & 7)) * 8)] = v;
    }
    __syncthreads();

    const int gbase = (k0 >> 5) * NF;
#pragma unroll
    for (int kk = 0; kk < 2; ++kk) {
      const int kc = kk * 4 + ahi;
      const short8 a =
          *(const short8*)&Atile[arow * 64 + ((kc ^ (arow & 7)) * 8)];
      const ushort* wp = Wp + ((size_t)(gbase + kk * NF) * 64 + lane) * 8;
#pragma unroll
      for (int nf = 0; nf < NF; ++nf) {
        const short8 b = *(const short8*)(wp + (size_t)nf * 64 * 8);
        acc[nf] = __builtin_amdgcn_mfma_f32_16x16x32_bf16(a, b, acc[nf], 0, 0, 0);
      }
    }
  }

  // epilogue: +bias, then row-wise log_softmax over 40 cols (16-lane quarter).
  const int ccol  = lane & 15;
  const int crow0 = brow + wave * 16 + (lane >> 4) * 4;
  float bv[NF];
#pragma unroll
  for (int nf = 0; nf < NF; ++nf) {
    const int col = nf * 16 + ccol;
    bv[nf] = (col < N) ? bias[col] : 0.f;
  }
  const bool v2ok = (32 + ccol) < N;
#pragma unroll
  for (int r = 0; r < 4; ++r) {
    const float v0 = acc[0][r] + bv[0];
    const float v1 = acc[1][r] + bv[1];
    const float v2 = acc[2][r] + bv[2];
    float m = fmaxf(v0, v1);
    if (v2ok) m = fmaxf(m, v2);
#pragma unroll
    for (int o = 8; o >= 1; o >>= 1) m = fmaxf(m, __shfl_xor(m, o, 64));
    float s = expf(v0 - m) + expf(v1 - m) + (v2ok ? expf(v2 - m) : 0.f);
#pragma unroll
    for (int o = 8; o >= 1; o >>= 1) s += __shfl_xor(s, o, 64);
    const float mls = m + logf(s);
    const int row = crow0 + r;
    if (row < M) {
      out[(size_t)row * N + ccol]      = v0 - mls;
      out[(size_t)row * N + 16 + ccol] = v1 - mls;
      if (v2ok) out[(size_t)row * N + 32 + ccol] = v2 - mls;
    }
  }
}

// ---------------- Aggregation: 4 edge-groups x 16 lanes x 8 features ----------------
// One wave per node; gathers bf16 h rows (16B/lane), f32 accumulate, bf16 out.
template <bool BIAS_RELU>
__global__ __launch_bounds__(256) void agg4_kernel(const ushort* __restrict__ h,
                                                   const int* __restrict__ offsets,
                                                   const int2* __restrict__ epair,
                                                   const float* __restrict__ dinv,
                                                   const float* __restrict__ bias,
                                                   ushort* __restrict__ out, int n) {
  const int wave = threadIdx.x >> 6;
  const int lane = threadIdx.x & 63;
  const int node = blockIdx.x * 4 + wave;
  if (node >= n) return;
  const int eg = lane >> 4;        // edge group 0..3
  const int f0 = (lane & 15) * 8;  // features f0..f0+7

  float acc[8];
#pragma unroll
  for (int j = 0; j < 8; ++j) acc[j] = 0.f;

  const int start = offsets[node];
  const int end   = offsets[node + 1];
  for (int e = start; e < end; e += 4) {
    const int ee = e + eg;
    if (ee < end) {  // uniform across the 16-lane group
      const int2 sw = epair[ee];
      const float w = __int_as_float(sw.y);
      const short8 hv = *(const short8*)&h[(size_t)sw.x * 128 + f0];
#pragma unroll
      for (int j = 0; j < 8; ++j) acc[j] = fmaf(bf2f((ushort)hv[j]), w, acc[j]);
    }
  }
  // reduce across the 4 edge groups
#pragma unroll
  for (int j = 0; j < 8; ++j) {
    acc[j] += __shfl_xor(acc[j], 16, 64);
    acc[j] += __shfl_xor(acc[j], 32, 64);
  }
  if (eg == 0) {
    const float di  = dinv[node];
    const float di2 = di * di;
    const short8 hs = *(const short8*)&h[(size_t)node * 128 + f0];
    ushort o[8];
#pragma unroll
    for (int j = 0; j < 8; ++j) {
      float a = fmaf(bf2f((ushort)hs[j]), di2, acc[j]);
      if (BIAS_RELU) a = fmaxf(a + bias[f0 + j], 0.f);
      o[j] = f2bf(a);
    }
    *(short8*)&out[(size_t)node * 128 + f0] = *(short8*)o;
  }
}

extern "C" void kernel_launch(void* const* d_in, const int* in_sizes, int n_in,
                              void* d_out, int out_size, void* d_ws, size_t ws_size,
                              hipStream_t stream) {
  const float* x  = (const float*)d_in[0];
  const int*   ei = (const int*)d_in[1];
  const float* W1 = (const float*)d_in[2];
  const float* b1 = (const float*)d_in[3];
  const float* W2 = (const float*)d_in[4];
  const float* b2 = (const float*)d_in[5];
  const float* W3 = (const float*)d_in[6];
  const float* b3 = (const float*)d_in[7];

  const int h1   = in_sizes[3];        // 128
  const int h2   = in_sizes[5];        // 128
  const int ncls = in_sizes[7];        // 40
  const int fin  = in_sizes[2] / h1;   // 256
  const int n    = in_sizes[0] / fin;  // 50000
  const int E    = in_sizes[1] / 2;    // 800000

  const int* src = ei;
  const int* dst = ei + E;

  char* p = (char*)d_ws;
  auto alloc = [&](size_t bytes) {
    char* r = p;
    p += (bytes + 255) & ~size_t(255);
    return r;
  };
  float*  dinv   = (float*)alloc((size_t)n * 4);
  int*    offs   = (int*)alloc((size_t)(n + 1) * 4);
  int*    bcount = (int*)alloc(256 * 4);
  int*    boffs  = (int*)alloc(257 * 4);
  int*    bcur   = (int*)alloc(256 * 4);
  int2*   staged = (int2*)alloc((size_t)E * 8);
  int2*   epair  = (int2*)alloc((size_t)E * 8);
  ushort* hf     = (ushort*)alloc((size_t)n * h1 * 2);  // ping
  ushort* hb     = (ushort*)alloc((size_t)n * h1 * 2);  // pong
  ushort* Wp1    = (ushort*)alloc((size_t)(fin / 32) * 8 * 64 * 8 * 2);
  ushort* Wp2    = (ushort*)alloc((size_t)(h1 / 32) * 8 * 64 * 8 * 2);
  ushort* Wp3    = (ushort*)alloc((size_t)(h2 / 32) * 3 * 64 * 8 * 2);

  const int nbuck = (n + 255) >> 8;        // 196 (requires n <= 65536)
  const int ebw   = (E + EPB - 1) / EPB;   // 196 edge workgroups

  // --- CSR build: 2-level bucket sort ---
  hipMemsetAsync(bcount, 0, 256 * 4, stream);
  bucket_hist_kernel<<<ebw, 256, 0, stream>>>(dst, bcount, E);
  bucket_scan_kernel<<<1, 256, 0, stream>>>(bcount, boffs, bcur, offs, nbuck, n);
  bucket_scatter_kernel<<<ebw, 256, 0, stream>>>(src, dst, bcur, staged, E, nbuck);
  bucket_csr_kernel<<<nbuck, 256, 0, stream>>>(staged, boffs, offs, dinv, n);
  bucket_fill_kernel<<<nbuck, 256, 0, stream>>>(staged, boffs, dinv, epair, n);

  // --- pack weights (fragment order, bf16) ---
  {
    int t1 = (fin / 32) * 8 * 64;
    int t2 = (h1 / 32) * 8 * 64;
    int t3 = (h2 / 32) * 3 * 64;
    pack_w_kernel<<<(t1 + 255) / 256, 256, 0, stream>>>(W1, Wp1, fin, h1, 8);
    pack_w_kernel<<<(t2 + 255) / 256, 256, 0, stream>>>(W2, Wp2, h1, h2, 8);
    pack_w_kernel<<<(t3 + 255) / 256, 256, 0, stream>>>(W3, Wp3, h2, ncls, 3);
  }

  const int gblocks = (n + 63) / 64;
  const int ablocks = (n + 3) / 4;

  // --- layer 1 ---
  mfma_gemm_kernel<8, true><<<gblocks, 256, 0, stream>>>(x, Wp1, hf, n, h1, fin);
  agg4_kernel<true><<<ablocks, 256, 0, stream>>>(hf, offs, epair, dinv, b1, hb, n);
  // --- layer 2 ---
  mfma_gemm_kernel<8, false><<<gblocks, 256, 0, stream>>>(hb, Wp2, hf, n, h2, h1);
  agg4_kernel<true><<<ablocks, 256, 0, stream>>>(hf, offs, epair, dinv, b2, hb, n);
  // --- layer 3: aggregate first (agg and GEMM commute), then GEMM+LSM ---
  agg4_kernel<false><<<ablocks, 256, 0, stream>>>(hb, offs, epair, dinv, nullptr, hf, n);
  mfma_gemm_lsm_kernel<<<gblocks, 256, 0, stream>>>(hf, Wp3, b3, (float*)d_out,
                                                    n, ncls, h2);
}

// Round 8
// 216.059 us; speedup vs baseline: 1.3387x; 1.0035x over previous
//
#include <hip/hip_runtime.h>
#include <cstdint>
#include <cstddef>
#include <cmath>

// ---------------------------------------------------------------------------
// GCN: 3 layers. CSR (by dst) built once, then:
//   L1: GEMM1(x 256->128, bf16 MFMA) -> agg(+b1,relu)
//   L2: GEMM2(128->128)              -> agg(+b2,relu)
//   L3: agg (no bias/relu)           -> GEMM3(128->40) + fused bias+log_softmax
// R2: MFMA GEMM + packed W. R3: bf16 h. R4: layer-3 commuted; agg4.
// R7: 2-level bucket sort CSR (single-XCD-owned scatter regions).
// R8: agg edge loop unrolled x2 (8 gathers in flight/wave) -- pure MLP boost,
//     no dependent dinv gather this time (norm packed in epair since R7).
// ---------------------------------------------------------------------------

typedef __attribute__((ext_vector_type(8))) short short8;
typedef __attribute__((ext_vector_type(4))) float f32x4;

constexpr int EPB = 4096;  // edges per workgroup in bucket hist/scatter

__device__ __forceinline__ ushort f2bf(float f) {
  union { float f; uint32_t u; } x; x.f = f;
  uint32_t r = x.u + 0x7fffu + ((x.u >> 16) & 1u);  // RNE
  return (ushort)(r >> 16);
}
__device__ __forceinline__ float bf2f(ushort u) {
  union { uint32_t u; float f; } x; x.u = ((uint32_t)u) << 16;
  return x.f;
}

// ---------------- CSR build: 2-level bucket sort ----------------
__global__ __launch_bounds__(256) void bucket_hist_kernel(const int* __restrict__ dst,
                                                          int* __restrict__ bucket_count,
                                                          int E) {
  __shared__ int h[256];
  const int t  = threadIdx.x;
  const int e0 = blockIdx.x * EPB;
  const int myE = min(EPB, E - e0);
  h[t] = 0;
  __syncthreads();
  for (int i = t; i < myE; i += 256) atomicAdd(&h[dst[e0 + i] >> 8], 1);
  __syncthreads();
  if (h[t]) atomicAdd(&bucket_count[t], h[t]);
}

__global__ __launch_bounds__(256) void bucket_scan_kernel(const int* __restrict__ bucket_count,
                                                          int* __restrict__ bucket_offs,
                                                          int* __restrict__ bucket_cursor,
                                                          int* __restrict__ offs,
                                                          int nbuck, int n) {
  __shared__ int s[256];
  const int t = threadIdx.x;
  const int c = (t < nbuck) ? bucket_count[t] : 0;
  s[t] = c;
  __syncthreads();
  for (int off = 1; off < 256; off <<= 1) {
    int v = (t >= off) ? s[t - off] : 0;
    __syncthreads();
    s[t] += v;
    __syncthreads();
  }
  if (t < nbuck) {
    bucket_offs[t]   = s[t] - c;
    bucket_cursor[t] = s[t] - c;
  }
  if (t == 255) {
    bucket_offs[nbuck] = s[255];
    offs[n] = s[255];
  }
}

__global__ __launch_bounds__(256) void bucket_scatter_kernel(const int* __restrict__ src,
                                                             const int* __restrict__ dst,
                                                             int* __restrict__ bucket_cursor,
                                                             int2* __restrict__ staged,
                                                             int E, int nbuck) {
  __shared__ int hist[256], s[256], lstart[256], cbase[256], lcur[256];
  __shared__ int2 stage[EPB];  // 32 KB
  const int t  = threadIdx.x;
  const int e0 = blockIdx.x * EPB;
  const int myE = min(EPB, E - e0);
  hist[t] = 0;
  __syncthreads();
  for (int i = t; i < myE; i += 256) atomicAdd(&hist[dst[e0 + i] >> 8], 1);
  __syncthreads();
  const int c = hist[t];
  s[t] = c;
  __syncthreads();
  for (int off = 1; off < 256; off <<= 1) {
    int v = (t >= off) ? s[t - off] : 0;
    __syncthreads();
    s[t] += v;
    __syncthreads();
  }
  lstart[t] = s[t] - c;
  lcur[t]   = s[t] - c;
  cbase[t]  = (c > 0 && t < nbuck) ? atomicAdd(&bucket_cursor[t], c) : 0;
  __syncthreads();
  for (int i = t; i < myE; i += 256) {
    const int sv = src[e0 + i], dv = dst[e0 + i];
    const int slot = atomicAdd(&lcur[dv >> 8], 1);
    stage[slot] = make_int2(sv, dv);
  }
  __syncthreads();
  for (int i = t; i < myE; i += 256) {
    const int2 sd = stage[i];
    const int b = sd.y >> 8;
    staged[cbase[b] + (i - lstart[b])] = sd;
  }
}

__global__ __launch_bounds__(256) void bucket_csr_kernel(const int2* __restrict__ staged,
                                                         const int* __restrict__ bucket_offs,
                                                         int* __restrict__ offs,
                                                         float* __restrict__ dinv, int n) {
  __shared__ int cnt[256], s[256];
  const int t = threadIdx.x, b = blockIdx.x;
  cnt[t] = 0;
  __syncthreads();
  const int ebeg = bucket_offs[b], eend = bucket_offs[b + 1];
  for (int i = ebeg + t; i < eend; i += 256) atomicAdd(&cnt[staged[i].y & 255], 1);
  __syncthreads();
  const int c = cnt[t];
  s[t] = c;
  __syncthreads();
  for (int off = 1; off < 256; off <<= 1) {
    int v = (t >= off) ? s[t - off] : 0;
    __syncthreads();
    s[t] += v;
    __syncthreads();
  }
  const int node = (b << 8) + t;
  if (node < n) {
    offs[node] = ebeg + s[t] - c;
    dinv[node] = rsqrtf((float)(c + 1));  // +1 self-loop
  }
}

__global__ __launch_bounds__(256) void bucket_fill_kernel(const int2* __restrict__ staged,
                                                          const int* __restrict__ bucket_offs,
                                                          const float* __restrict__ dinv,
                                                          int2* __restrict__ epair, int n) {
  __shared__ int cnt[256], s[256], cur[256];
  const int t = threadIdx.x, b = blockIdx.x;
  cnt[t] = 0;
  __syncthreads();
  const int ebeg = bucket_offs[b], eend = bucket_offs[b + 1];
  for (int i = ebeg + t; i < eend; i += 256) atomicAdd(&cnt[staged[i].y & 255], 1);
  __syncthreads();
  const int c = cnt[t];
  s[t] = c;
  __syncthreads();
  for (int off = 1; off < 256; off <<= 1) {
    int v = (t >= off) ? s[t - off] : 0;
    __syncthreads();
    s[t] += v;
    __syncthreads();
  }
  cur[t] = ebeg + s[t] - c;
  __syncthreads();
  for (int i = ebeg + t; i < eend; i += 256) {
    const int2 sd = staged[i];
    const int pos = atomicAdd(&cur[sd.y & 255], 1);
    epair[pos] = make_int2(sd.x, __float_as_int(dinv[sd.x] * dinv[sd.y]));
  }
}

// ---------------- W pre-pack into MFMA B-fragment order ----------------
__global__ __launch_bounds__(256) void pack_w_kernel(const float* __restrict__ W,
                                                     ushort* __restrict__ Wp,
                                                     int K, int N, int NF) {
  const int idx  = blockIdx.x * blockDim.x + threadIdx.x;
  const int lane = idx & 63;
  const int nf   = (idx >> 6) % NF;
  const int g    = idx / (64 * NF);
  if (g * 32 >= K) return;
  const int n  = nf * 16 + (lane & 15);
  const int kb = g * 32 + (lane >> 4) * 8;
  ushort v[8];
#pragma unroll
  for (int j = 0; j < 8; ++j) {
    const float f = (n < N) ? W[(size_t)(kb + j) * N + n] : 0.f;
    v[j] = f2bf(f);
  }
  *(short8*)&Wp[((size_t)(g * NF + nf) * 64 + lane) * 8] = *(short8*)v;
}

// ---------------- MFMA GEMM: C[M,N] = A[M,K] @ W[K,N], bf16 out ----------------
template <int NF, bool AF32>
__global__ __launch_bounds__(256) void mfma_gemm_kernel(const void* __restrict__ Av,
                                                        const ushort* __restrict__ Wp,
                                                        ushort* __restrict__ C,
                                                        int M, int N, int K) {
  __shared__ ushort Atile[64 * 64];
  const int tid  = threadIdx.x;
  const int lane = tid & 63;
  const int wave = tid >> 6;
  const int brow = blockIdx.x * 64;

  f32x4 acc[NF];
#pragma unroll
  for (int nf = 0; nf < NF; ++nf) acc[nf] = (f32x4){0.f, 0.f, 0.f, 0.f};

  const int arow = wave * 16 + (lane & 15);
  const int ahi  = lane >> 4;
  const int row0 = tid >> 3;
  const int kc0  = tid & 7;

  for (int k0 = 0; k0 < K; k0 += 64) {
    if (k0) __syncthreads();
#pragma unroll
    for (int c = 0; c < 2; ++c) {
      const int row = row0 + c * 32;
      const int gr  = brow + row;
      short8 v = (short8){0, 0, 0, 0, 0, 0, 0, 0};
      if (gr < M) {
        if constexpr (AF32) {
          const float* A = (const float*)Av + (size_t)gr * K + k0 + kc0 * 8;
          const float4 f0 = *(const float4*)A;
          const float4 f1 = *(const float4*)(A + 4);
          v[0] = (short)f2bf(f0.x); v[1] = (short)f2bf(f0.y);
          v[2] = (short)f2bf(f0.z); v[3] = (short)f2bf(f0.w);
          v[4] = (short)f2bf(f1.x); v[5] = (short)f2bf(f1.y);
          v[6] = (short)f2bf(f1.z); v[7] = (short)f2bf(f1.w);
        } else {
          v = *(const short8*)((const ushort*)Av + (size_t)gr * K + k0 + kc0 * 8);
        }
      }
      *(short8*)&Atile[row * 64 + ((kc0 ^ (row & 7)) * 8)] = v;
    }
    __syncthreads();

    const int gbase = (k0 >> 5) * NF;
#pragma unroll
    for (int kk = 0; kk < 2; ++kk) {
      const int kc = kk * 4 + ahi;
      const short8 a =
          *(const short8*)&Atile[arow * 64 + ((kc ^ (arow & 7)) * 8)];
      const ushort* wp = Wp + ((size_t)(gbase + kk * NF) * 64 + lane) * 8;
#pragma unroll
      for (int nf = 0; nf < NF; ++nf) {
        const short8 b = *(const short8*)(wp + (size_t)nf * 64 * 8);
        acc[nf] = __builtin_amdgcn_mfma_f32_16x16x32_bf16(a, b, acc[nf], 0, 0, 0);
      }
    }
  }

  const int crow0 = brow + wave * 16 + (lane >> 4) * 4;
  const int ccol  = lane & 15;
#pragma unroll
  for (int nf = 0; nf < NF; ++nf) {
    const int col = nf * 16 + ccol;
    if (col < N) {
#pragma unroll
      for (int r = 0; r < 4; ++r) {
        const int row = crow0 + r;
        if (row < M) C[(size_t)row * N + col] = f2bf(acc[nf][r]);
      }
    }
  }
}

// ------- GEMM3 + fused bias + log_softmax: out[M,40] = lsm(A[M,128] @ W3 + b3) -------
__global__ __launch_bounds__(256) void mfma_gemm_lsm_kernel(const ushort* __restrict__ A,
                                                            const ushort* __restrict__ Wp,
                                                            const float* __restrict__ bias,
                                                            float* __restrict__ out,
                                                            int M, int N, int K) {
  constexpr int NF = 3;
  __shared__ ushort Atile[64 * 64];
  const int tid  = threadIdx.x;
  const int lane = tid & 63;
  const int wave = tid >> 6;
  const int brow = blockIdx.x * 64;

  f32x4 acc[NF];
#pragma unroll
  for (int nf = 0; nf < NF; ++nf) acc[nf] = (f32x4){0.f, 0.f, 0.f, 0.f};

  const int arow = wave * 16 + (lane & 15);
  const int ahi  = lane >> 4;
  const int row0 = tid >> 3;
  const int kc0  = tid & 7;

  for (int k0 = 0; k0 < K; k0 += 64) {
    if (k0) __syncthreads();
#pragma unroll
    for (int c = 0; c < 2; ++c) {
      const int row = row0 + c * 32;
      const int gr  = brow + row;
      short8 v = (short8){0, 0, 0, 0, 0, 0, 0, 0};
      if (gr < M)
        v = *(const short8*)&A[(size_t)gr * K + k0 + kc0 * 8];
      *(short8*)&Atile[row * 64 + ((kc0 ^ (row & 7)) * 8)] = v;
    }
    __syncthreads();

    const int gbase = (k0 >> 5) * NF;
#pragma unroll
    for (int kk = 0; kk < 2; ++kk) {
      const int kc = kk * 4 + ahi;
      const short8 a =
          *(const short8*)&Atile[arow * 64 + ((kc ^ (arow & 7)) * 8)];
      const ushort* wp = Wp + ((size_t)(gbase + kk * NF) * 64 + lane) * 8;
#pragma unroll
      for (int nf = 0; nf < NF; ++nf) {
        const short8 b = *(const short8*)(wp + (size_t)nf * 64 * 8);
        acc[nf] = __builtin_amdgcn_mfma_f32_16x16x32_bf16(a, b, acc[nf], 0, 0, 0);
      }
    }
  }

  // epilogue: +bias, then row-wise log_softmax over 40 cols (16-lane quarter).
  const int ccol  = lane & 15;
  const int crow0 = brow + wave * 16 + (lane >> 4) * 4;
  float bv[NF];
#pragma unroll
  for (int nf = 0; nf < NF; ++nf) {
    const int col = nf * 16 + ccol;
    bv[nf] = (col < N) ? bias[col] : 0.f;
  }
  const bool v2ok = (32 + ccol) < N;
#pragma unroll
  for (int r = 0; r < 4; ++r) {
    const float v0 = acc[0][r] + bv[0];
    const float v1 = acc[1][r] + bv[1];
    const float v2 = acc[2][r] + bv[2];
    float m = fmaxf(v0, v1);
    if (v2ok) m = fmaxf(m, v2);
#pragma unroll
    for (int o = 8; o >= 1; o >>= 1) m = fmaxf(m, __shfl_xor(m, o, 64));
    float s = expf(v0 - m) + expf(v1 - m) + (v2ok ? expf(v2 - m) : 0.f);
#pragma unroll
    for (int o = 8; o >= 1; o >>= 1) s += __shfl_xor(s, o, 64);
    const float mls = m + logf(s);
    const int row = crow0 + r;
    if (row < M) {
      out[(size_t)row * N + ccol]      = v0 - mls;
      out[(size_t)row * N + 16 + ccol] = v1 - mls;
      if (v2ok) out[(size_t)row * N + 32 + ccol] = v2 - mls;
    }
  }
}

// ---------------- Aggregation: 4 edge-groups x 16 lanes x 8 features ----------------
// One wave per node; 2x unrolled edge loop (8 gathers in flight per wave).
template <bool BIAS_RELU>
__global__ __launch_bounds__(256) void agg4_kernel(const ushort* __restrict__ h,
                                                   const int* __restrict__ offsets,
                                                   const int2* __restrict__ epair,
                                                   const float* __restrict__ dinv,
                                                   const float* __restrict__ bias,
                                                   ushort* __restrict__ out, int n) {
  const int wave = threadIdx.x >> 6;
  const int lane = threadIdx.x & 63;
  const int node = blockIdx.x * 4 + wave;
  if (node >= n) return;
  const int eg = lane >> 4;        // edge group 0..3
  const int f0 = (lane & 15) * 8;  // features f0..f0+7

  float acc[8];
#pragma unroll
  for (int j = 0; j < 8; ++j) acc[j] = 0.f;

  const int start = offsets[node];
  const int end   = offsets[node + 1];
  for (int eb = start; eb < end; eb += 8) {
    const int e0 = eb + eg;
    const int e1 = e0 + 4;
    if (e0 < end) {
      const int2  sw0 = epair[e0];
      const float w0  = __int_as_float(sw0.y);
      const short8 hv0 = *(const short8*)&h[(size_t)sw0.x * 128 + f0];
      if (e1 < end) {
        const int2  sw1 = epair[e1];
        const float w1  = __int_as_float(sw1.y);
        const short8 hv1 = *(const short8*)&h[(size_t)sw1.x * 128 + f0];
#pragma unroll
        for (int j = 0; j < 8; ++j) {
          acc[j] = fmaf(bf2f((ushort)hv0[j]), w0, acc[j]);
          acc[j] = fmaf(bf2f((ushort)hv1[j]), w1, acc[j]);
        }
      } else {
#pragma unroll
        for (int j = 0; j < 8; ++j) acc[j] = fmaf(bf2f((ushort)hv0[j]), w0, acc[j]);
      }
    }
  }
  // reduce across the 4 edge groups
#pragma unroll
  for (int j = 0; j < 8; ++j) {
    acc[j] += __shfl_xor(acc[j], 16, 64);
    acc[j] += __shfl_xor(acc[j], 32, 64);
  }
  if (eg == 0) {
    const float di  = dinv[node];
    const float di2 = di * di;
    const short8 hs = *(const short8*)&h[(size_t)node * 128 + f0];
    ushort o[8];
#pragma unroll
    for (int j = 0; j < 8; ++j) {
      float a = fmaf(bf2f((ushort)hs[j]), di2, acc[j]);
      if (BIAS_RELU) a = fmaxf(a + bias[f0 + j], 0.f);
      o[j] = f2bf(a);
    }
    *(short8*)&out[(size_t)node * 128 + f0] = *(short8*)o;
  }
}

extern "C" void kernel_launch(void* const* d_in, const int* in_sizes, int n_in,
                              void* d_out, int out_size, void* d_ws, size_t ws_size,
                              hipStream_t stream) {
  const float* x  = (const float*)d_in[0];
  const int*   ei = (const int*)d_in[1];
  const float* W1 = (const float*)d_in[2];
  const float* b1 = (const float*)d_in[3];
  const float* W2 = (const float*)d_in[4];
  const float* b2 = (const float*)d_in[5];
  const float* W3 = (const float*)d_in[6];
  const float* b3 = (const float*)d_in[7];

  const int h1   = in_sizes[3];        // 128
  const int h2   = in_sizes[5];        // 128
  const int ncls = in_sizes[7];        // 40
  const int fin  = in_sizes[2] / h1;   // 256
  const int n    = in_sizes[0] / fin;  // 50000
  const int E    = in_sizes[1] / 2;    // 800000

  const int* src = ei;
  const int* dst = ei + E;

  char* p = (char*)d_ws;
  auto alloc = [&](size_t bytes) {
    char* r = p;
    p += (bytes + 255) & ~size_t(255);
    return r;
  };
  float*  dinv   = (float*)alloc((size_t)n * 4);
  int*    offs   = (int*)alloc((size_t)(n + 1) * 4);
  int*    bcount = (int*)alloc(256 * 4);
  int*    boffs  = (int*)alloc(257 * 4);
  int*    bcur   = (int*)alloc(256 * 4);
  int2*   staged = (int2*)alloc((size_t)E * 8);
  int2*   epair  = (int2*)alloc((size_t)E * 8);
  ushort* hf     = (ushort*)alloc((size_t)n * h1 * 2);  // ping
  ushort* hb     = (ushort*)alloc((size_t)n * h1 * 2);  // pong
  ushort* Wp1    = (ushort*)alloc((size_t)(fin / 32) * 8 * 64 * 8 * 2);
  ushort* Wp2    = (ushort*)alloc((size_t)(h1 / 32) * 8 * 64 * 8 * 2);
  ushort* Wp3    = (ushort*)alloc((size_t)(h2 / 32) * 3 * 64 * 8 * 2);

  const int nbuck = (n + 255) >> 8;        // 196 (requires n <= 65536)
  const int ebw   = (E + EPB - 1) / EPB;   // 196 edge workgroups

  // --- CSR build: 2-level bucket sort ---
  hipMemsetAsync(bcount, 0, 256 * 4, stream);
  bucket_hist_kernel<<<ebw, 256, 0, stream>>>(dst, bcount, E);
  bucket_scan_kernel<<<1, 256, 0, stream>>>(bcount, boffs, bcur, offs, nbuck, n);
  bucket_scatter_kernel<<<ebw, 256, 0, stream>>>(src, dst, bcur, staged, E, nbuck);
  bucket_csr_kernel<<<nbuck, 256, 0, stream>>>(staged, boffs, offs, dinv, n);
  bucket_fill_kernel<<<nbuck, 256, 0, stream>>>(staged, boffs, dinv, epair, n);

  // --- pack weights (fragment order, bf16) ---
  {
    int t1 = (fin / 32) * 8 * 64;
    int t2 = (h1 / 32) * 8 * 64;
    int t3 = (h2 / 32) * 3 * 64;
    pack_w_kernel<<<(t1 + 255) / 256, 256, 0, stream>>>(W1, Wp1, fin, h1, 8);
    pack_w_kernel<<<(t2 + 255) / 256, 256, 0, stream>>>(W2, Wp2, h1, h2, 8);
    pack_w_kernel<<<(t3 + 255) / 256, 256, 0, stream>>>(W3, Wp3, h2, ncls, 3);
  }

  const int gblocks = (n + 63) / 64;
  const int ablocks = (n + 3) / 4;

  // --- layer 1 ---
  mfma_gemm_kernel<8, true><<<gblocks, 256, 0, stream>>>(x, Wp1, hf, n, h1, fin);
  agg4_kernel<true><<<ablocks, 256, 0, stream>>>(hf, offs, epair, dinv, b1, hb, n);
  // --- layer 2 ---
  mfma_gemm_kernel<8, false><<<gblocks, 256, 0, stream>>>(hb, Wp2, hf, n, h2, h1);
  agg4_kernel<true><<<ablocks, 256, 0, stream>>>(hf, offs, epair, dinv, b2, hb, n);
  // --- layer 3: aggregate first (agg and GEMM commute), then GEMM+LSM ---
  agg4_kernel<false><<<ablocks, 256, 0, stream>>>(hb, offs, epair, dinv, nullptr, hf, n);
  mfma_gemm_lsm_kernel<<<gblocks, 256, 0, stream>>>(hf, Wp3, b3, (float*)d_out,
                                                    n, ncls, h2);
}